// Round 18
// baseline (275.849 us; speedup 1.0000x reference)
//
#include <hip/hip_runtime.h>

#define NP1 20000
#define NP2 80000
#define KN  27

typedef unsigned short ushort;
typedef unsigned int   uint;
typedef __attribute__((ext_vector_type(8))) short short8v;
typedef __attribute__((ext_vector_type(4))) float f32x4;

__device__ __forceinline__ ushort f2bf(float x) {
    union { float f; uint u; } v; v.f = x;
    uint r = v.u + 0x7fffu + ((v.u >> 16) & 1u);
    return (ushort)(r >> 16);
}
__device__ __forceinline__ float bf2f(ushort s) {
    union { uint u; float f; } v; v.u = ((uint)s) << 16;
    return v.f;
}
__device__ __forceinline__ void gload_lds16(const void* g, void* l) {
    __builtin_amdgcn_global_load_lds(
        (const __attribute__((address_space(1))) unsigned int*)g,
        (__attribute__((address_space(3))) unsigned int*)l, 16, 0, 0);
}
// bijective chunked XCD swizzle (m204)
__device__ __forceinline__ int xcd_swz(int b, int nb) {
    int q = nb >> 3, r = nb & 7;
    int x = b & 7, p = b >> 3;
    return (x < r) ? x * (q + 1) + p : r * (q + 1) + (x - r) * q + p;
}

// ---------------------------------------------------------------------------
// setup: ALL independent front-matter in one launch.
//   blocks [0,270)    : LDS-tiled transpose of the 270 conv taps -> bf16 swz
//   blocks [270,314)  : small-weight preps (W0a/W1a/W0b/W1b/s1) + out/zpage zero
//   blocks [314,2814) : gather_curr (prior_emb[curr_occ] -> bf16 fA)
// ---------------------------------------------------------------------------
__global__ __launch_bounds__(256) void setup_k(
    const float* __restrict__ Wp, const float* __restrict__ Wt,
    ushort* __restrict__ dstp, ushort* __restrict__ dstt,
    const float* __restrict__ W0a, const float* __restrict__ W1a,
    const float* __restrict__ W0b, const float* __restrict__ W1b,
    const float* __restrict__ s1,
    ushort* __restrict__ W0aT, ushort* __restrict__ W1aT,
    ushort* __restrict__ W0bT, ushort* __restrict__ W1bT,
    ushort* __restrict__ s1bT,
    const float* __restrict__ prior_emb, const int* __restrict__ curr_occ,
    ushort* __restrict__ fA, float* __restrict__ outp,
    ushort* __restrict__ zpage)
{
    __shared__ float sT[64 * 65];
    const int b = blockIdx.x, t = threadIdx.x;

    if (b < 270) {
        const float* W = (b < 135) ? Wp : Wt;
        ushort* dst    = (b < 135) ? dstp : dstt;
        int k = (b < 135) ? b : b - 135;
        const float* src = W + (size_t)k * 4096;
        #pragma unroll
        for (int p = 0; p < 16; ++p) {
            int i = t + p * 256;
            sT[(i >> 6) * 65 + (i & 63)] = src[i];
        }
        __syncthreads();
        ushort* d = dst + (size_t)k * 4096;
        #pragma unroll
        for (int p = 0; p < 16; ++p) {
            int o = t + p * 256;
            int c = o >> 6, jj = o & 63;
            int j = (((jj >> 3) ^ (c & 7)) << 3) | (jj & 7);
            d[o] = f2bf(sT[j * 65 + c]);
        }
    } else if (b < 314) {
        int bb = b - 270;
        if (bb == 0) {
            if (t == 0) *outp = 0.0f;
            if (t < 64) ((uint*)zpage)[t] = 0u;
        }
        if (bb < 32) {
            const float* W = (bb < 16) ? W0a : W1a;
            ushort* dst    = (bb < 16) ? W0aT : W1aT;
            int i = (bb & 15) * 256 + t;
            int c = i >> 6, jj = i & 63;
            int j = (((jj >> 3) ^ (c & 7)) << 3) | (jj & 7);
            dst[i] = f2bf(W[j * 64 + c]);
        } else if (bb < 40) {
            const float* W = (bb < 36) ? W0b : W1b;
            ushort* dst    = (bb < 36) ? W0bT : W1bT;
            int i = (bb - ((bb < 36) ? 32 : 36)) * 256 + t;
            int c = i >> 6, jj = i & 63;
            int j = (((jj >> 3) ^ (c & 7)) << 3) | (jj & 7);
            dst[i] = f2bf(W[j * 16 + c]);
        } else {
            int i = (bb - 40) * 256 + t;
            int e = i >> 6, jj = i & 63;
            int j = (((jj >> 3) ^ (e & 7)) << 3) | (jj & 7);
            s1bT[i] = f2bf(s1[e * 64 + j]);
        }
    } else {
        int i = (b - 314) * 256 + t;
        int row = i >> 5, cp = (i & 31) * 2;
        const float* src = prior_emb + (size_t)curr_occ[row] * 64 + cp;
        uint pk = (uint)f2bf(src[0]) | ((uint)f2bf(src[1]) << 16);
        *(uint*)((char*)fA + (size_t)row * 128 + cp * 2) = pk;
    }
}

// ---------------------------------------------------------------------------
// gather_next (depends on N1 output -> separate launch)
// ---------------------------------------------------------------------------
__global__ __launch_bounds__(256) void gather_next_k(
    const ushort* __restrict__ f, const int* __restrict__ parent_idx,
    const int* __restrict__ next_oct, const float* __restrict__ temb8,
    ushort* __restrict__ out)
{
    int i = blockIdx.x * 256 + threadIdx.x;
    if (i >= NP2 * 32) return;
    int row = i >> 5, cp = (i & 31) * 2;
    const ushort* fs = f + (size_t)parent_idx[row] * 64 + cp;
    const float* ts = temb8 + (size_t)next_oct[row] * 64 + cp;
    float v0 = bf2f(fs[0]) + ts[0];
    float v1 = bf2f(fs[1]) + ts[1];
    uint pk = (uint)f2bf(v0) | ((uint)f2bf(v1) << 16);
    *(uint*)((char*)out + (size_t)row * 128 + cp * 2) = pk;
}

// ---------------------------------------------------------------------------
// Register-A MFMA sparse conv, optional column-split.
// NW waves; CG col-groups; wave = 16 rows x (64/CG) cols.
// LDS holds only W (2x8KB dbuf, single __syncthreads per tap).
// ---------------------------------------------------------------------------
template<int NW, int CG>
__global__ __launch_bounds__(NW * 64) void spconv_reg_k(
    const ushort* __restrict__ feats, const int* __restrict__ nbr,
    const ushort* __restrict__ Wsw, const ushort* __restrict__ res,
    ushort* __restrict__ out, const ushort* __restrict__ zpage, int nblocks)
{
    constexpr int ROWS   = (NW / CG) * 16;
    constexpr int NB     = 4 / CG;
    constexpr int WLOADS = 8192 / (NW * 64 * 16);

    __shared__ __align__(16) char sW[2 * 8192];

    const int t = threadIdx.x;
    const int w = t >> 6, l = t & 63;
    const int wg = xcd_swz(blockIdx.x, nblocks);
    const int row0 = wg * ROWS;
    const int lr = l & 15, lhi = l >> 4;
    const int colbase = (w % CG) * (NB * 16);
    const int rw = w / CG;
    const int ch0 = lhi ^ (lr & 7);
    const int ch1 = (4 + lhi) ^ (lr & 7);

    const int* nbrow = nbr + (size_t)(row0 + rw * 16 + lr) * KN;

    f32x4 acc[NB];
    #pragma unroll
    for (int b = 0; b < NB; ++b) acc[b] = (f32x4)0.0f;

    short8v aC0, aC1, aN0, aN1;
    int idxA, idxB;

    #define LOADA(IDX, CHOFF) \
        (*(const short8v*)(((IDX) >= 0 ? (const char*)feats + (size_t)(IDX) * 128 \
                                       : (const char*)zpage) + ((CHOFF) + lhi) * 16))

    {
        int id0 = nbrow[0];
        aC0 = LOADA(id0, 0);
        aC1 = LOADA(id0, 4);
        idxA = nbrow[1];
        const char* wsrc = (const char*)Wsw;
        #pragma unroll
        for (int i = 0; i < WLOADS; ++i) {
            int off = (w * WLOADS + i) * 1024;
            gload_lds16(wsrc + off + l * 16, sW + off);
        }
    }

    for (int k = 0; k < KN; ++k) {
        char* cur = sW + (k & 1) * 8192;
        char* nxt = sW + ((k + 1) & 1) * 8192;

        __syncthreads();   // drains W(k) stage + A(k) prefetch; rendezvous

        if (k < KN - 1) {
            const char* wsrc = (const char*)Wsw + (size_t)(k + 1) * 8192;
            #pragma unroll
            for (int i = 0; i < WLOADS; ++i) {
                int off = (w * WLOADS + i) * 1024;
                gload_lds16(wsrc + off + l * 16, nxt + off);
            }
            aN0 = LOADA(idxA, 0);
            aN1 = LOADA(idxA, 4);
        }
        if (k < KN - 2) idxB = nbrow[k + 2];

        __builtin_amdgcn_s_setprio(1);
        {
            short8v b0[NB];
            #pragma unroll
            for (int nb = 0; nb < NB; ++nb)
                b0[nb] = *(const short8v*)(cur + (colbase + nb * 16 + lr) * 128 + ch0 * 16);
            #pragma unroll
            for (int nb = 0; nb < NB; ++nb)
                acc[nb] = __builtin_amdgcn_mfma_f32_16x16x32_bf16(aC0, b0[nb], acc[nb], 0, 0, 0);
            short8v b1[NB];
            #pragma unroll
            for (int nb = 0; nb < NB; ++nb)
                b1[nb] = *(const short8v*)(cur + (colbase + nb * 16 + lr) * 128 + ch1 * 16);
            #pragma unroll
            for (int nb = 0; nb < NB; ++nb)
                acc[nb] = __builtin_amdgcn_mfma_f32_16x16x32_bf16(aC1, b1[nb], acc[nb], 0, 0, 0);
        }
        __builtin_amdgcn_s_setprio(0);

        aC0 = aN0; aC1 = aN1; idxA = idxB;
    }
    #undef LOADA

    #pragma unroll
    for (int nb = 0; nb < NB; ++nb) {
        #pragma unroll
        for (int r = 0; r < 4; ++r) {
            int rg = row0 + rw * 16 + lhi * 4 + r;
            int c = colbase + nb * 16 + lr;
            float v = acc[nb][r];
            if (res != nullptr) v += bf2f(res[(size_t)rg * 64 + c]);
            v = fmaxf(v, 0.0f);
            float o = __shfl_xor(v, 1);
            if (!(l & 1)) {
                uint pk = (uint)f2bf(v) | ((uint)f2bf(o) << 16);
                *(uint*)((char*)out + (size_t)rg * 128 + (c << 1)) = pk;
            }
        }
    }
}

// ---------------------------------------------------------------------------
// Head v2: per-wave independent (16 rows/wave), G in registers, one barrier.
// ---------------------------------------------------------------------------
__global__ __launch_bounds__(512) void head_v2_k(
    const ushort* __restrict__ G, const int* __restrict__ next_occ,
    const ushort* __restrict__ Wsmall,
    const float* __restrict__ b0a, const float* __restrict__ b1a,
    const float* __restrict__ b0b, const float* __restrict__ b1b,
    const int* __restrict__ n_points, float* __restrict__ outp)
{
    __shared__ __align__(16) char sm[48288];
    char*  sWs = sm;                                   // 22528
    char*  sHb = sm + 22528;                           // 8 * 2048
    float* sLb = (float*)(sm + 38912);                 // 8 * 272 floats
    float* sBf = (float*)(sm + 47616);                 // 160
    float* sRed = (float*)(sm + 48256);                // 8

    const int t = threadIdx.x;
    const int w = t >> 6, l = t & 63;
    const int row0 = blockIdx.x * 128;
    const int lr = l & 15, lhi = l >> 4;
    char*  sH = sHb + w * 2048;
    float* sL = sLb + w * 272;

    const int myrow = row0 + w * 16 + lr;
    const int occ_l = next_occ[myrow];

    short8v aG0 = *(const short8v*)((const char*)G + (size_t)myrow * 128 + lhi * 16);
    short8v aG1 = *(const short8v*)((const char*)G + (size_t)myrow * 128 + (4 + lhi) * 16);

    for (int i = w; i < 22; i += 8)
        gload_lds16((const char*)Wsmall + i * 1024 + l * 16, sWs + i * 1024);
    if (t < 64)       sBf[t] = b0a[t];
    else if (t < 128) sBf[t] = b1a[t - 64];
    else if (t < 144) sBf[128 + (t - 128)] = b0b[t - 128];
    else if (t < 160) sBf[144 + (t - 144)] = b1b[t - 144];
    __syncthreads();

    float bacc = 0.0f;

    // ======== stage 0 ========
    {
        f32x4 a0[4];
        #pragma unroll
        for (int b = 0; b < 4; ++b) a0[b] = (f32x4)0.0f;
        #pragma unroll
        for (int j0 = 0; j0 < 2; ++j0) {
            short8v a = j0 ? aG1 : aG0;
            #pragma unroll
            for (int nb = 0; nb < 4; ++nb) {
                int c = nb * 16 + lr;
                int ch = (j0 * 4 + lhi) ^ (c & 7);
                short8v b = *(const short8v*)(sWs + c * 128 + ch * 16);   // W0aT
                a0[nb] = __builtin_amdgcn_mfma_f32_16x16x32_bf16(a, b, a0[nb], 0, 0, 0);
            }
        }
        #pragma unroll
        for (int nb = 0; nb < 4; ++nb) {
            float bias = sBf[nb * 16 + lr];
            #pragma unroll
            for (int r = 0; r < 4; ++r) {
                int row = lhi * 4 + r;
                int j = nb * 16 + lr;
                float v = fmaxf(a0[nb][r] + bias, 0.0f);
                float o = __shfl_xor(v, 1);
                if (!(l & 1)) {
                    uint pk = (uint)f2bf(v) | ((uint)f2bf(o) << 16);
                    *(uint*)(sH + row * 128 + (((j >> 3) ^ (row & 7)) << 4)
                             + (j & 7) * 2) = pk;
                }
            }
        }
        asm volatile("s_waitcnt lgkmcnt(0)" ::: "memory");
        __builtin_amdgcn_sched_barrier(0);
        f32x4 lg = (f32x4)0.0f;
        #pragma unroll
        for (int j0 = 0; j0 < 2; ++j0) {
            int ch = (j0 * 4 + lhi) ^ (lr & 7);
            short8v a = *(const short8v*)(sH + lr * 128 + ch * 16);
            short8v b = *(const short8v*)(sWs + 16384 + lr * 128 + ch * 16); // W0bT
            lg = __builtin_amdgcn_mfma_f32_16x16x32_bf16(a, b, lg, 0, 0, 0);
        }
        #pragma unroll
        for (int r = 0; r < 4; ++r)
            sL[(lhi * 4 + r) * 17 + lr] = lg[r] + sBf[128 + lr];
        asm volatile("s_waitcnt lgkmcnt(0)" ::: "memory");
        __builtin_amdgcn_sched_barrier(0);
        {
            int tgt = occ_l & 15;
            float lv[16], mx = -1e30f;
            #pragma unroll
            for (int c = 0; c < 16; ++c) {
                lv[c] = sL[lr * 17 + c];
                mx = fmaxf(mx, lv[c]);
            }
            float ssum = 0.0f, lt = lv[0];
            #pragma unroll
            for (int c = 0; c < 16; ++c) {
                ssum += __expf(lv[c] - mx);
                lt = (c == tgt) ? lv[c] : lt;
            }
            float p = __expf(lt - mx) / ssum;
            float bits = fminf(fmaxf(-log2f(p + 1e-10f), 0.0f), 50.0f);
            if (l < 16) bacc += bits;
        }
    }

    // ======== stage 1 ========
    {
        f32x4 a1[4];
        #pragma unroll
        for (int b = 0; b < 4; ++b) a1[b] = (f32x4)0.0f;
        int low_l = occ_l & 15;
        #pragma unroll
        for (int j0 = 0; j0 < 2; ++j0) {
            short8v g8 = j0 ? aG1 : aG0;
            int che = (j0 * 4 + lhi) ^ (low_l & 7);
            short8v e8 = *(const short8v*)(sWs + 20480 + low_l * 128 + che * 16); // s1b
            short8v a;
            #pragma unroll
            for (int e = 0; e < 8; ++e) {
                float f = bf2f((ushort)g8[e]) + bf2f((ushort)e8[e]);
                a[e] = (short)f2bf(f);
            }
            #pragma unroll
            for (int nb = 0; nb < 4; ++nb) {
                int c = nb * 16 + lr;
                int ch = (j0 * 4 + lhi) ^ (c & 7);
                short8v b = *(const short8v*)(sWs + 8192 + c * 128 + ch * 16); // W1aT
                a1[nb] = __builtin_amdgcn_mfma_f32_16x16x32_bf16(a, b, a1[nb], 0, 0, 0);
            }
        }
        #pragma unroll
        for (int nb = 0; nb < 4; ++nb) {
            float bias = sBf[64 + nb * 16 + lr];
            #pragma unroll
            for (int r = 0; r < 4; ++r) {
                int row = lhi * 4 + r;
                int j = nb * 16 + lr;
                float v = fmaxf(a1[nb][r] + bias, 0.0f);
                float o = __shfl_xor(v, 1);
                if (!(l & 1)) {
                    uint pk = (uint)f2bf(v) | ((uint)f2bf(o) << 16);
                    *(uint*)(sH + row * 128 + (((j >> 3) ^ (row & 7)) << 4)
                             + (j & 7) * 2) = pk;
                }
            }
        }
        asm volatile("s_waitcnt lgkmcnt(0)" ::: "memory");
        __builtin_amdgcn_sched_barrier(0);
        f32x4 lg = (f32x4)0.0f;
        #pragma unroll
        for (int j0 = 0; j0 < 2; ++j0) {
            int ch = (j0 * 4 + lhi) ^ (lr & 7);
            short8v a = *(const short8v*)(sH + lr * 128 + ch * 16);
            short8v b = *(const short8v*)(sWs + 18432 + lr * 128 + ch * 16); // W1bT
            lg = __builtin_amdgcn_mfma_f32_16x16x32_bf16(a, b, lg, 0, 0, 0);
        }
        #pragma unroll
        for (int r = 0; r < 4; ++r)
            sL[(lhi * 4 + r) * 17 + lr] = lg[r] + sBf[144 + lr];
        asm volatile("s_waitcnt lgkmcnt(0)" ::: "memory");
        __builtin_amdgcn_sched_barrier(0);
        {
            int tgt = occ_l >> 4;
            float lv[16], mx = -1e30f;
            #pragma unroll
            for (int c = 0; c < 16; ++c) {
                lv[c] = sL[lr * 17 + c];
                mx = fmaxf(mx, lv[c]);
            }
            float ssum = 0.0f, lt = lv[0];
            #pragma unroll
            for (int c = 0; c < 16; ++c) {
                ssum += __expf(lv[c] - mx);
                lt = (c == tgt) ? lv[c] : lt;
            }
            float p = __expf(lt - mx) / ssum;
            float bits = fminf(fmaxf(-log2f(p + 1e-10f), 0.0f), 50.0f);
            if (l < 16) bacc += bits;
        }
    }

    #pragma unroll
    for (int s = 1; s < 64; s <<= 1) bacc += __shfl_xor(bacc, s);
    if (l == 0) sRed[w] = bacc;
    __syncthreads();
    if (t == 0) {
        float s = 0.0f;
        #pragma unroll
        for (int i = 0; i < 8; ++i) s += sRed[i];
        atomicAdd(outp, s / (float)(*n_points));
    }
}

// ---------------------------------------------------------------------------
extern "C" void kernel_launch(void* const* d_in, const int* in_sizes, int n_in,
                              void* d_out, int out_size, void* d_ws, size_t ws_size,
                              hipStream_t stream)
{
    const float* prior_emb = (const float*)d_in[0];
    const float* temb8     = (const float*)d_in[1];
    const float* Wp        = (const float*)d_in[2];
    const float* Wt        = (const float*)d_in[3];
    const float* W0a       = (const float*)d_in[4];
    const float* b0a       = (const float*)d_in[5];
    const float* W0b       = (const float*)d_in[6];
    const float* b0b       = (const float*)d_in[7];
    const float* W1a       = (const float*)d_in[8];
    const float* b1a       = (const float*)d_in[9];
    const float* W1b       = (const float*)d_in[10];
    const float* b1b       = (const float*)d_in[11];
    const float* s1_emb    = (const float*)d_in[12];
    const int*   curr_occ  = (const int*)d_in[13];
    const int*   next_occ  = (const int*)d_in[14];
    const int*   next_oct  = (const int*)d_in[15];
    const int*   parent    = (const int*)d_in[16];
    const int*   nbr_curr  = (const int*)d_in[17];
    const int*   nbr_next  = (const int*)d_in[18];
    const int*   n_points  = (const int*)d_in[19];
    float* out = (float*)d_out;

    char* wsb = (char*)d_ws;
    ushort* zpage = (ushort*)wsb;
    size_t off = 256;
    ushort* WpT = (ushort*)(wsb + off); off += (size_t)135 * 4096 * 2;
    ushort* WtT = (ushort*)(wsb + off); off += (size_t)135 * 4096 * 2;
    ushort* Wsmall = (ushort*)(wsb + off);
    ushort* W0aT = Wsmall;
    ushort* W1aT = Wsmall + 4096;
    ushort* W0bT = Wsmall + 8192;
    ushort* W1bT = Wsmall + 9216;
    ushort* s1bT = Wsmall + 10240;
    off += 11264 * 2;
    off = (off + 255) & ~(size_t)255;
    ushort* fA = (ushort*)(wsb + off); off += (size_t)NP1 * 64 * 2;
    ushort* fB = (ushort*)(wsb + off); off += (size_t)NP1 * 64 * 2;
    ushort* fC = (ushort*)(wsb + off); off += (size_t)NP1 * 64 * 2;
    ushort* gA = (ushort*)(wsb + off); off += (size_t)NP2 * 64 * 2;
    ushort* gB = (ushort*)(wsb + off); off += (size_t)NP2 * 64 * 2;
    ushort* gC = (ushort*)(wsb + off); off += (size_t)NP2 * 64 * 2;

    // one setup launch: tap preps + small preps + gather_curr + out/zpage zero
    setup_k<<<2814, 256, 0, stream>>>(Wp, Wt, WpT, WtT,
                                      W0a, W1a, W0b, W1b, s1_emb,
                                      W0aT, W1aT, W0bT, W1bT, s1bT,
                                      prior_emb, curr_occ, fA, out, zpage);

    const size_t WT = (size_t)KN * 4096;
    // N1: <8,4> wave = 16 rows x 16 cols, 32 rows/block, 625 blocks, 5000 waves.
    spconv_reg_k<8,4><<<625, 512, 0, stream>>>(fA, nbr_curr, WpT + 0 * WT, nullptr, fB, zpage, 625);
    spconv_reg_k<8,4><<<625, 512, 0, stream>>>(fB, nbr_curr, WpT + 1 * WT, nullptr, fC, zpage, 625);
    spconv_reg_k<8,4><<<625, 512, 0, stream>>>(fC, nbr_curr, WpT + 2 * WT, fB,      fA, zpage, 625);
    spconv_reg_k<8,4><<<625, 512, 0, stream>>>(fA, nbr_curr, WpT + 3 * WT, nullptr, fC, zpage, 625);
    spconv_reg_k<8,4><<<625, 512, 0, stream>>>(fC, nbr_curr, WpT + 4 * WT, fA,      fB, zpage, 625);

    gather_next_k<<<(NP2 * 32 + 255) / 256, 256, 0, stream>>>(fB, parent, next_oct, temb8, gA);

    // N2: <8,1> 128 rows/block, 625 blocks, 5000 waves, 32 waves/CU.
    spconv_reg_k<8,1><<<625, 512, 0, stream>>>(gA, nbr_next, WtT + 0 * WT, nullptr, gB, zpage, 625);
    spconv_reg_k<8,1><<<625, 512, 0, stream>>>(gB, nbr_next, WtT + 1 * WT, nullptr, gC, zpage, 625);
    spconv_reg_k<8,1><<<625, 512, 0, stream>>>(gC, nbr_next, WtT + 2 * WT, gB,      gA, zpage, 625);
    spconv_reg_k<8,1><<<625, 512, 0, stream>>>(gA, nbr_next, WtT + 3 * WT, nullptr, gC, zpage, 625);
    spconv_reg_k<8,1><<<625, 512, 0, stream>>>(gC, nbr_next, WtT + 4 * WT, gA,      gB, zpage, 625);

    head_v2_k<<<625, 512, 0, stream>>>(gB, next_occ, Wsmall,
                                       b0a, b1a, b0b, b1b, n_points, out);
}

// Round 19
// 247.933 us; speedup vs baseline: 1.1126x; 1.1126x over previous
//
#include <hip/hip_runtime.h>

#define NP1 20000
#define NP2 80000
#define KN  27

typedef unsigned short ushort;
typedef unsigned int   uint;
typedef __attribute__((ext_vector_type(8))) short short8v;
typedef __attribute__((ext_vector_type(4))) float f32x4;

__device__ __forceinline__ ushort f2bf(float x) {
    union { float f; uint u; } v; v.f = x;
    uint r = v.u + 0x7fffu + ((v.u >> 16) & 1u);
    return (ushort)(r >> 16);
}
__device__ __forceinline__ float bf2f(ushort s) {
    union { uint u; float f; } v; v.u = ((uint)s) << 16;
    return v.f;
}
__device__ __forceinline__ void gload_lds16(const void* g, void* l) {
    __builtin_amdgcn_global_load_lds(
        (const __attribute__((address_space(1))) unsigned int*)g,
        (__attribute__((address_space(3))) unsigned int*)l, 16, 0, 0);
}
// bijective chunked XCD swizzle (m204)
__device__ __forceinline__ int xcd_swz(int b, int nb) {
    int q = nb >> 3, r = nb & 7;
    int x = b & 7, p = b >> 3;
    return (x < r) ? x * (q + 1) + p : r * (q + 1) + (x - r) * q + p;
}

// ---------------------------------------------------------------------------
// setup: ALL independent front-matter in one launch.
//   blocks [0,270)    : LDS-tiled transpose of the 270 conv taps -> bf16 swz
//   blocks [270,314)  : small-weight preps (W0a/W1a/W0b/W1b/s1) + out/zpage zero
//   blocks [314,2814) : gather_curr (prior_emb[curr_occ] -> bf16 fA)
// ---------------------------------------------------------------------------
__global__ __launch_bounds__(256) void setup_k(
    const float* __restrict__ Wp, const float* __restrict__ Wt,
    ushort* __restrict__ dstp, ushort* __restrict__ dstt,
    const float* __restrict__ W0a, const float* __restrict__ W1a,
    const float* __restrict__ W0b, const float* __restrict__ W1b,
    const float* __restrict__ s1,
    ushort* __restrict__ W0aT, ushort* __restrict__ W1aT,
    ushort* __restrict__ W0bT, ushort* __restrict__ W1bT,
    ushort* __restrict__ s1bT,
    const float* __restrict__ prior_emb, const int* __restrict__ curr_occ,
    ushort* __restrict__ fA, float* __restrict__ outp,
    ushort* __restrict__ zpage)
{
    __shared__ float sT[64 * 65];
    const int b = blockIdx.x, t = threadIdx.x;

    if (b < 270) {
        const float* W = (b < 135) ? Wp : Wt;
        ushort* dst    = (b < 135) ? dstp : dstt;
        int k = (b < 135) ? b : b - 135;
        const float* src = W + (size_t)k * 4096;
        #pragma unroll
        for (int p = 0; p < 16; ++p) {
            int i = t + p * 256;
            sT[(i >> 6) * 65 + (i & 63)] = src[i];
        }
        __syncthreads();
        ushort* d = dst + (size_t)k * 4096;
        #pragma unroll
        for (int p = 0; p < 16; ++p) {
            int o = t + p * 256;
            int c = o >> 6, jj = o & 63;
            int j = (((jj >> 3) ^ (c & 7)) << 3) | (jj & 7);
            d[o] = f2bf(sT[j * 65 + c]);
        }
    } else if (b < 314) {
        int bb = b - 270;
        if (bb == 0) {
            if (t == 0) *outp = 0.0f;
            if (t < 64) ((uint*)zpage)[t] = 0u;
        }
        if (bb < 32) {
            const float* W = (bb < 16) ? W0a : W1a;
            ushort* dst    = (bb < 16) ? W0aT : W1aT;
            int i = (bb & 15) * 256 + t;
            int c = i >> 6, jj = i & 63;
            int j = (((jj >> 3) ^ (c & 7)) << 3) | (jj & 7);
            dst[i] = f2bf(W[j * 64 + c]);
        } else if (bb < 40) {
            const float* W = (bb < 36) ? W0b : W1b;
            ushort* dst    = (bb < 36) ? W0bT : W1bT;
            int i = (bb - ((bb < 36) ? 32 : 36)) * 256 + t;
            int c = i >> 6, jj = i & 63;
            int j = (((jj >> 3) ^ (c & 7)) << 3) | (jj & 7);
            dst[i] = f2bf(W[j * 16 + c]);
        } else {
            int i = (bb - 40) * 256 + t;
            int e = i >> 6, jj = i & 63;
            int j = (((jj >> 3) ^ (e & 7)) << 3) | (jj & 7);
            s1bT[i] = f2bf(s1[e * 64 + j]);
        }
    } else {
        int i = (b - 314) * 256 + t;
        int row = i >> 5, cp = (i & 31) * 2;
        const float* src = prior_emb + (size_t)curr_occ[row] * 64 + cp;
        uint pk = (uint)f2bf(src[0]) | ((uint)f2bf(src[1]) << 16);
        *(uint*)((char*)fA + (size_t)row * 128 + cp * 2) = pk;
    }
}

// ---------------------------------------------------------------------------
// gather_next (depends on N1 output -> separate launch)
// ---------------------------------------------------------------------------
__global__ __launch_bounds__(256) void gather_next_k(
    const ushort* __restrict__ f, const int* __restrict__ parent_idx,
    const int* __restrict__ next_oct, const float* __restrict__ temb8,
    ushort* __restrict__ out)
{
    int i = blockIdx.x * 256 + threadIdx.x;
    if (i >= NP2 * 32) return;
    int row = i >> 5, cp = (i & 31) * 2;
    const ushort* fs = f + (size_t)parent_idx[row] * 64 + cp;
    const float* ts = temb8 + (size_t)next_oct[row] * 64 + cp;
    float v0 = bf2f(fs[0]) + ts[0];
    float v1 = bf2f(fs[1]) + ts[1];
    uint pk = (uint)f2bf(v0) | ((uint)f2bf(v1) << 16);
    *(uint*)((char*)out + (size_t)row * 128 + cp * 2) = pk;
}

// ---------------------------------------------------------------------------
// Register-A MFMA sparse conv, optional column-split.
// NW waves; CG col-groups (1: wave = 16 rows x 64 cols; 2: 16 rows x 32 cols).
// LDS holds only W (2x8KB dbuf, single __syncthreads per tap).
// ---------------------------------------------------------------------------
template<int NW, int CG>
__global__ __launch_bounds__(NW * 64) void spconv_reg_k(
    const ushort* __restrict__ feats, const int* __restrict__ nbr,
    const ushort* __restrict__ Wsw, const ushort* __restrict__ res,
    ushort* __restrict__ out, const ushort* __restrict__ zpage, int nblocks)
{
    constexpr int ROWS   = (NW / CG) * 16;
    constexpr int NB     = 4 / CG;
    constexpr int WLOADS = 8192 / (NW * 64 * 16);

    __shared__ __align__(16) char sW[2 * 8192];

    const int t = threadIdx.x;
    const int w = t >> 6, l = t & 63;
    const int wg = xcd_swz(blockIdx.x, nblocks);
    const int row0 = wg * ROWS;
    const int lr = l & 15, lhi = l >> 4;
    const int colbase = (w % CG) * (NB * 16);
    const int rw = w / CG;
    const int ch0 = lhi ^ (lr & 7);
    const int ch1 = (4 + lhi) ^ (lr & 7);

    const int* nbrow = nbr + (size_t)(row0 + rw * 16 + lr) * KN;

    f32x4 acc[NB];
    #pragma unroll
    for (int b = 0; b < NB; ++b) acc[b] = (f32x4)0.0f;

    short8v aC0, aC1, aN0, aN1;
    int idxA, idxB;

    #define LOADA(IDX, CHOFF) \
        (*(const short8v*)(((IDX) >= 0 ? (const char*)feats + (size_t)(IDX) * 128 \
                                       : (const char*)zpage) + ((CHOFF) + lhi) * 16))

    {
        int id0 = nbrow[0];
        aC0 = LOADA(id0, 0);
        aC1 = LOADA(id0, 4);
        idxA = nbrow[1];
        const char* wsrc = (const char*)Wsw;
        #pragma unroll
        for (int i = 0; i < WLOADS; ++i) {
            int off = (w * WLOADS + i) * 1024;
            gload_lds16(wsrc + off + l * 16, sW + off);
        }
    }

    for (int k = 0; k < KN; ++k) {
        char* cur = sW + (k & 1) * 8192;
        char* nxt = sW + ((k + 1) & 1) * 8192;

        __syncthreads();   // drains W(k) stage + A(k) prefetch; rendezvous

        if (k < KN - 1) {
            const char* wsrc = (const char*)Wsw + (size_t)(k + 1) * 8192;
            #pragma unroll
            for (int i = 0; i < WLOADS; ++i) {
                int off = (w * WLOADS + i) * 1024;
                gload_lds16(wsrc + off + l * 16, nxt + off);
            }
            aN0 = LOADA(idxA, 0);
            aN1 = LOADA(idxA, 4);
        }
        if (k < KN - 2) idxB = nbrow[k + 2];

        __builtin_amdgcn_s_setprio(1);
        {
            short8v b0[NB];
            #pragma unroll
            for (int nb = 0; nb < NB; ++nb)
                b0[nb] = *(const short8v*)(cur + (colbase + nb * 16 + lr) * 128 + ch0 * 16);
            #pragma unroll
            for (int nb = 0; nb < NB; ++nb)
                acc[nb] = __builtin_amdgcn_mfma_f32_16x16x32_bf16(aC0, b0[nb], acc[nb], 0, 0, 0);
            short8v b1[NB];
            #pragma unroll
            for (int nb = 0; nb < NB; ++nb)
                b1[nb] = *(const short8v*)(cur + (colbase + nb * 16 + lr) * 128 + ch1 * 16);
            #pragma unroll
            for (int nb = 0; nb < NB; ++nb)
                acc[nb] = __builtin_amdgcn_mfma_f32_16x16x32_bf16(aC1, b1[nb], acc[nb], 0, 0, 0);
        }
        __builtin_amdgcn_s_setprio(0);

        aC0 = aN0; aC1 = aN1; idxA = idxB;
    }
    #undef LOADA

    #pragma unroll
    for (int nb = 0; nb < NB; ++nb) {
        #pragma unroll
        for (int r = 0; r < 4; ++r) {
            int rg = row0 + rw * 16 + lhi * 4 + r;
            int c = colbase + nb * 16 + lr;
            float v = acc[nb][r];
            if (res != nullptr) v += bf2f(res[(size_t)rg * 64 + c]);
            v = fmaxf(v, 0.0f);
            float o = __shfl_xor(v, 1);
            if (!(l & 1)) {
                uint pk = (uint)f2bf(v) | ((uint)f2bf(o) << 16);
                *(uint*)((char*)out + (size_t)rg * 128 + (c << 1)) = pk;
            }
        }
    }
}

// ---------------------------------------------------------------------------
// Head v2: per-wave independent (16 rows/wave), G in registers, one barrier.
// ---------------------------------------------------------------------------
__global__ __launch_bounds__(512) void head_v2_k(
    const ushort* __restrict__ G, const int* __restrict__ next_occ,
    const ushort* __restrict__ Wsmall,
    const float* __restrict__ b0a, const float* __restrict__ b1a,
    const float* __restrict__ b0b, const float* __restrict__ b1b,
    const int* __restrict__ n_points, float* __restrict__ outp)
{
    __shared__ __align__(16) char sm[48288];
    char*  sWs = sm;                                   // 22528
    char*  sHb = sm + 22528;                           // 8 * 2048
    float* sLb = (float*)(sm + 38912);                 // 8 * 272 floats
    float* sBf = (float*)(sm + 47616);                 // 160
    float* sRed = (float*)(sm + 48256);                // 8

    const int t = threadIdx.x;
    const int w = t >> 6, l = t & 63;
    const int row0 = blockIdx.x * 128;
    const int lr = l & 15, lhi = l >> 4;
    char*  sH = sHb + w * 2048;
    float* sL = sLb + w * 272;

    const int myrow = row0 + w * 16 + lr;
    const int occ_l = next_occ[myrow];

    short8v aG0 = *(const short8v*)((const char*)G + (size_t)myrow * 128 + lhi * 16);
    short8v aG1 = *(const short8v*)((const char*)G + (size_t)myrow * 128 + (4 + lhi) * 16);

    for (int i = w; i < 22; i += 8)
        gload_lds16((const char*)Wsmall + i * 1024 + l * 16, sWs + i * 1024);
    if (t < 64)       sBf[t] = b0a[t];
    else if (t < 128) sBf[t] = b1a[t - 64];
    else if (t < 144) sBf[128 + (t - 128)] = b0b[t - 128];
    else if (t < 160) sBf[144 + (t - 144)] = b1b[t - 144];
    __syncthreads();

    float bacc = 0.0f;

    // ======== stage 0 ========
    {
        f32x4 a0[4];
        #pragma unroll
        for (int b = 0; b < 4; ++b) a0[b] = (f32x4)0.0f;
        #pragma unroll
        for (int j0 = 0; j0 < 2; ++j0) {
            short8v a = j0 ? aG1 : aG0;
            #pragma unroll
            for (int nb = 0; nb < 4; ++nb) {
                int c = nb * 16 + lr;
                int ch = (j0 * 4 + lhi) ^ (c & 7);
                short8v b = *(const short8v*)(sWs + c * 128 + ch * 16);   // W0aT
                a0[nb] = __builtin_amdgcn_mfma_f32_16x16x32_bf16(a, b, a0[nb], 0, 0, 0);
            }
        }
        #pragma unroll
        for (int nb = 0; nb < 4; ++nb) {
            float bias = sBf[nb * 16 + lr];
            #pragma unroll
            for (int r = 0; r < 4; ++r) {
                int row = lhi * 4 + r;
                int j = nb * 16 + lr;
                float v = fmaxf(a0[nb][r] + bias, 0.0f);
                float o = __shfl_xor(v, 1);
                if (!(l & 1)) {
                    uint pk = (uint)f2bf(v) | ((uint)f2bf(o) << 16);
                    *(uint*)(sH + row * 128 + (((j >> 3) ^ (row & 7)) << 4)
                             + (j & 7) * 2) = pk;
                }
            }
        }
        asm volatile("s_waitcnt lgkmcnt(0)" ::: "memory");
        __builtin_amdgcn_sched_barrier(0);
        f32x4 lg = (f32x4)0.0f;
        #pragma unroll
        for (int j0 = 0; j0 < 2; ++j0) {
            int ch = (j0 * 4 + lhi) ^ (lr & 7);
            short8v a = *(const short8v*)(sH + lr * 128 + ch * 16);
            short8v b = *(const short8v*)(sWs + 16384 + lr * 128 + ch * 16); // W0bT
            lg = __builtin_amdgcn_mfma_f32_16x16x32_bf16(a, b, lg, 0, 0, 0);
        }
        #pragma unroll
        for (int r = 0; r < 4; ++r)
            sL[(lhi * 4 + r) * 17 + lr] = lg[r] + sBf[128 + lr];
        asm volatile("s_waitcnt lgkmcnt(0)" ::: "memory");
        __builtin_amdgcn_sched_barrier(0);
        {
            int tgt = occ_l & 15;
            float lv[16], mx = -1e30f;
            #pragma unroll
            for (int c = 0; c < 16; ++c) {
                lv[c] = sL[lr * 17 + c];
                mx = fmaxf(mx, lv[c]);
            }
            float ssum = 0.0f, lt = lv[0];
            #pragma unroll
            for (int c = 0; c < 16; ++c) {
                ssum += __expf(lv[c] - mx);
                lt = (c == tgt) ? lv[c] : lt;
            }
            float p = __expf(lt - mx) / ssum;
            float bits = fminf(fmaxf(-log2f(p + 1e-10f), 0.0f), 50.0f);
            if (l < 16) bacc += bits;
        }
    }

    // ======== stage 1 ========
    {
        f32x4 a1[4];
        #pragma unroll
        for (int b = 0; b < 4; ++b) a1[b] = (f32x4)0.0f;
        int low_l = occ_l & 15;
        #pragma unroll
        for (int j0 = 0; j0 < 2; ++j0) {
            short8v g8 = j0 ? aG1 : aG0;
            int che = (j0 * 4 + lhi) ^ (low_l & 7);
            short8v e8 = *(const short8v*)(sWs + 20480 + low_l * 128 + che * 16); // s1b
            short8v a;
            #pragma unroll
            for (int e = 0; e < 8; ++e) {
                float f = bf2f((ushort)g8[e]) + bf2f((ushort)e8[e]);
                a[e] = (short)f2bf(f);
            }
            #pragma unroll
            for (int nb = 0; nb < 4; ++nb) {
                int c = nb * 16 + lr;
                int ch = (j0 * 4 + lhi) ^ (c & 7);
                short8v b = *(const short8v*)(sWs + 8192 + c * 128 + ch * 16); // W1aT
                a1[nb] = __builtin_amdgcn_mfma_f32_16x16x32_bf16(a, b, a1[nb], 0, 0, 0);
            }
        }
        #pragma unroll
        for (int nb = 0; nb < 4; ++nb) {
            float bias = sBf[64 + nb * 16 + lr];
            #pragma unroll
            for (int r = 0; r < 4; ++r) {
                int row = lhi * 4 + r;
                int j = nb * 16 + lr;
                float v = fmaxf(a1[nb][r] + bias, 0.0f);
                float o = __shfl_xor(v, 1);
                if (!(l & 1)) {
                    uint pk = (uint)f2bf(v) | ((uint)f2bf(o) << 16);
                    *(uint*)(sH + row * 128 + (((j >> 3) ^ (row & 7)) << 4)
                             + (j & 7) * 2) = pk;
                }
            }
        }
        asm volatile("s_waitcnt lgkmcnt(0)" ::: "memory");
        __builtin_amdgcn_sched_barrier(0);
        f32x4 lg = (f32x4)0.0f;
        #pragma unroll
        for (int j0 = 0; j0 < 2; ++j0) {
            int ch = (j0 * 4 + lhi) ^ (lr & 7);
            short8v a = *(const short8v*)(sH + lr * 128 + ch * 16);
            short8v b = *(const short8v*)(sWs + 18432 + lr * 128 + ch * 16); // W1bT
            lg = __builtin_amdgcn_mfma_f32_16x16x32_bf16(a, b, lg, 0, 0, 0);
        }
        #pragma unroll
        for (int r = 0; r < 4; ++r)
            sL[(lhi * 4 + r) * 17 + lr] = lg[r] + sBf[144 + lr];
        asm volatile("s_waitcnt lgkmcnt(0)" ::: "memory");
        __builtin_amdgcn_sched_barrier(0);
        {
            int tgt = occ_l >> 4;
            float lv[16], mx = -1e30f;
            #pragma unroll
            for (int c = 0; c < 16; ++c) {
                lv[c] = sL[lr * 17 + c];
                mx = fmaxf(mx, lv[c]);
            }
            float ssum = 0.0f, lt = lv[0];
            #pragma unroll
            for (int c = 0; c < 16; ++c) {
                ssum += __expf(lv[c] - mx);
                lt = (c == tgt) ? lv[c] : lt;
            }
            float p = __expf(lt - mx) / ssum;
            float bits = fminf(fmaxf(-log2f(p + 1e-10f), 0.0f), 50.0f);
            if (l < 16) bacc += bits;
        }
    }

    #pragma unroll
    for (int s = 1; s < 64; s <<= 1) bacc += __shfl_xor(bacc, s);
    if (l == 0) sRed[w] = bacc;
    __syncthreads();
    if (t == 0) {
        float s = 0.0f;
        #pragma unroll
        for (int i = 0; i < 8; ++i) s += sRed[i];
        atomicAdd(outp, s / (float)(*n_points));
    }
}

// ---------------------------------------------------------------------------
extern "C" void kernel_launch(void* const* d_in, const int* in_sizes, int n_in,
                              void* d_out, int out_size, void* d_ws, size_t ws_size,
                              hipStream_t stream)
{
    const float* prior_emb = (const float*)d_in[0];
    const float* temb8     = (const float*)d_in[1];
    const float* Wp        = (const float*)d_in[2];
    const float* Wt        = (const float*)d_in[3];
    const float* W0a       = (const float*)d_in[4];
    const float* b0a       = (const float*)d_in[5];
    const float* W0b       = (const float*)d_in[6];
    const float* b0b       = (const float*)d_in[7];
    const float* W1a       = (const float*)d_in[8];
    const float* b1a       = (const float*)d_in[9];
    const float* W1b       = (const float*)d_in[10];
    const float* b1b       = (const float*)d_in[11];
    const float* s1_emb    = (const float*)d_in[12];
    const int*   curr_occ  = (const int*)d_in[13];
    const int*   next_occ  = (const int*)d_in[14];
    const int*   next_oct  = (const int*)d_in[15];
    const int*   parent    = (const int*)d_in[16];
    const int*   nbr_curr  = (const int*)d_in[17];
    const int*   nbr_next  = (const int*)d_in[18];
    const int*   n_points  = (const int*)d_in[19];
    float* out = (float*)d_out;

    char* wsb = (char*)d_ws;
    ushort* zpage = (ushort*)wsb;
    size_t off = 256;
    ushort* WpT = (ushort*)(wsb + off); off += (size_t)135 * 4096 * 2;
    ushort* WtT = (ushort*)(wsb + off); off += (size_t)135 * 4096 * 2;
    ushort* Wsmall = (ushort*)(wsb + off);
    ushort* W0aT = Wsmall;
    ushort* W1aT = Wsmall + 4096;
    ushort* W0bT = Wsmall + 8192;
    ushort* W1bT = Wsmall + 9216;
    ushort* s1bT = Wsmall + 10240;
    off += 11264 * 2;
    off = (off + 255) & ~(size_t)255;
    ushort* fA = (ushort*)(wsb + off); off += (size_t)NP1 * 64 * 2;
    ushort* fB = (ushort*)(wsb + off); off += (size_t)NP1 * 64 * 2;
    ushort* fC = (ushort*)(wsb + off); off += (size_t)NP1 * 64 * 2;
    ushort* gA = (ushort*)(wsb + off); off += (size_t)NP2 * 64 * 2;
    ushort* gB = (ushort*)(wsb + off); off += (size_t)NP2 * 64 * 2;
    ushort* gC = (ushort*)(wsb + off); off += (size_t)NP2 * 64 * 2;

    // one setup launch: tap preps + small preps + gather_curr + out/zpage zero
    setup_k<<<2814, 256, 0, stream>>>(Wp, Wt, WpT, WtT,
                                      W0a, W1a, W0b, W1b, s1_emb,
                                      W0aT, W1aT, W0bT, W1bT, s1bT,
                                      prior_emb, curr_occ, fA, out, zpage);

    const size_t WT = (size_t)KN * 4096;
    // N1: <4,2> wave = 16 rows x 32 cols, 32 rows/block, 625 blocks, 2500 waves.
    spconv_reg_k<4,2><<<625, 256, 0, stream>>>(fA, nbr_curr, WpT + 0 * WT, nullptr, fB, zpage, 625);
    spconv_reg_k<4,2><<<625, 256, 0, stream>>>(fB, nbr_curr, WpT + 1 * WT, nullptr, fC, zpage, 625);
    spconv_reg_k<4,2><<<625, 256, 0, stream>>>(fC, nbr_curr, WpT + 2 * WT, fB,      fA, zpage, 625);
    spconv_reg_k<4,2><<<625, 256, 0, stream>>>(fA, nbr_curr, WpT + 3 * WT, nullptr, fC, zpage, 625);
    spconv_reg_k<4,2><<<625, 256, 0, stream>>>(fC, nbr_curr, WpT + 4 * WT, fA,      fB, zpage, 625);

    gather_next_k<<<(NP2 * 32 + 255) / 256, 256, 0, stream>>>(fB, parent, next_oct, temb8, gA);

    // N2: <8,1> 128 rows/block, 625 blocks, 5000 waves, 32 waves/CU.
    spconv_reg_k<8,1><<<625, 512, 0, stream>>>(gA, nbr_next, WtT + 0 * WT, nullptr, gB, zpage, 625);
    spconv_reg_k<8,1><<<625, 512, 0, stream>>>(gB, nbr_next, WtT + 1 * WT, nullptr, gC, zpage, 625);
    spconv_reg_k<8,1><<<625, 512, 0, stream>>>(gC, nbr_next, WtT + 2 * WT, gB,      gA, zpage, 625);
    spconv_reg_k<8,1><<<625, 512, 0, stream>>>(gA, nbr_next, WtT + 3 * WT, nullptr, gC, zpage, 625);
    spconv_reg_k<8,1><<<625, 512, 0, stream>>>(gC, nbr_next, WtT + 4 * WT, gA,      gB, zpage, 625);

    head_v2_k<<<625, 512, 0, stream>>>(gB, next_occ, Wsmall,
                                       b0a, b1a, b0b, b1b, n_points, out);
}